// Round 6
// baseline (77569.769 us; speedup 1.0000x reference)
//
#include <hip/hip_runtime.h>
#include <cstddef>

#define LRC 0.001f
#define DEC 0.99f

typedef float vf4 __attribute__((ext_vector_type(4)));

// ---------------- workspace layout (float offsets) ----------------
static const size_t OFF_Z1T  = 0;           // [2048][32] transposed partials
static const size_t OFF_Z2TP = 65536;
static const size_t OFF_Z2TQ = 131072;
static const size_t OFF_Z3TP = 196608;
static const size_t OFF_Z3TQ = 262144;
static const size_t OFF_Z4TP = 327680;      // [768][32]
static const size_t OFF_Z4TQ = 352256;
static const size_t OFF_H1F = 376832;
static const size_t OFF_H1Q = 378880;
static const size_t OFF_H2F = 380928;
static const size_t OFF_H2Q = 382976;
static const size_t OFF_H3F = 385024;
static const size_t OFF_H3Q0 = 387072;
static const size_t OFF_D4F = 389120;
static const size_t OFF_D4Q = 389888;
static const size_t OFF_D3F = 390656;
static const size_t OFF_D3Q = 392704;
static const size_t OFF_D2F = 394752;
static const size_t OFF_D2Q = 396800;
static const size_t OFF_D1F = 398848;
static const size_t OFF_D1Q = 400896;
static const size_t OFF_NSQ = 402944;
static const size_t OFF_SL3 = 402960;
static const size_t OFF_SL2 = 403216;
static const size_t OFF_SL1 = 403472;
static const size_t OFF_BUF = 403728;
static const size_t OFF_CONDF = 403730;
static const size_t OFF_MSUM = 403732;      // [32][768]
static const size_t OFF_HA  = 428308;       // tail GEMM buffer
static const size_t OFF_BAR = OFF_HA;       // 1024 ints (TTT only)
static const size_t OFF_H3Q1 = OFF_HA + 1024;
static const size_t OFF_HB  = 2525460;

// ---------------- MALL-coherent access (sc0 sc1 = bypass L1+L2) --------------
#define PIN(v) asm volatile("" : "+v"(v))
__device__ __forceinline__ void vmwait() { asm volatile("s_waitcnt vmcnt(0)" ::: "memory"); }
__device__ __forceinline__ float ld_nw(const float* p) {
    float v;
    asm volatile("global_load_dword %0, %1, off sc0 sc1" : "=&v"(v) : "v"(p) : "memory");
    return v;
}
__device__ __forceinline__ vf4 ld4_nw(const float* p) {
    vf4 v;
    asm volatile("global_load_dwordx4 %0, %1, off sc0 sc1" : "=&v"(v) : "v"(p) : "memory");
    return v;
}
__device__ __forceinline__ float ld_cv(const float* p) {
    float v = ld_nw(p); vmwait(); PIN(v); return v;
}
__device__ __forceinline__ vf4 ld4_cv(const float* p) {
    vf4 v = ld4_nw(p); vmwait(); PIN(v); return v;
}
// 8 vf4 at 1KB stride (2048-wide row slice), no wait
__device__ __forceinline__ void ldrow_nw(const float* p, vf4* r) {
    const float* q = p + 1024;
    asm volatile(
        "global_load_dwordx4 %0, %8, off sc0 sc1\n\t"
        "global_load_dwordx4 %1, %8, off offset:1024 sc0 sc1\n\t"
        "global_load_dwordx4 %2, %8, off offset:2048 sc0 sc1\n\t"
        "global_load_dwordx4 %3, %8, off offset:3072 sc0 sc1\n\t"
        "global_load_dwordx4 %4, %9, off sc0 sc1\n\t"
        "global_load_dwordx4 %5, %9, off offset:1024 sc0 sc1\n\t"
        "global_load_dwordx4 %6, %9, off offset:2048 sc0 sc1\n\t"
        "global_load_dwordx4 %7, %9, off offset:3072 sc0 sc1"
        : "=&v"(r[0]), "=&v"(r[1]), "=&v"(r[2]), "=&v"(r[3]),
          "=&v"(r[4]), "=&v"(r[5]), "=&v"(r[6]), "=&v"(r[7])
        : "v"(p), "v"(q) : "memory");
}
__device__ __forceinline__ void ldrow3_nw(const float* p, vf4& a, vf4& b, vf4& c) {
    asm volatile(
        "global_load_dwordx4 %0, %3, off sc0 sc1\n\t"
        "global_load_dwordx4 %1, %3, off offset:1024 sc0 sc1\n\t"
        "global_load_dwordx4 %2, %3, off offset:2048 sc0 sc1"
        : "=&v"(a), "=&v"(b), "=&v"(c) : "v"(p) : "memory");
}
__device__ __forceinline__ void st_cv(float* p, float v) {
    asm volatile("global_store_dword %0, %1, off sc0 sc1" :: "v"(p), "v"(v) : "memory");
}
__device__ __forceinline__ void st_cv4(float* p, vf4 v) {
    asm volatile("global_store_dwordx4 %0, %1, off sc0 sc1" :: "v"(p), "v"(v) : "memory");
}
__device__ __forceinline__ float sum4(vf4 v) { return v.x + v.y + v.z + v.w; }

__device__ float block_reduce_512(float v) {
    __shared__ float red[512];
    int t = threadIdx.x;
    red[t] = v;
    __syncthreads();
    for (int s = 256; s > 0; s >>= 1) {
        if (t < s) red[t] += red[t + s];
        __syncthreads();
    }
    float r = red[0];
    __syncthreads();
    return r;
}

// ---- fence-free grid barrier: RELAXED atomics only ----
__device__ inline void gbar(int* bar, int bi) {
    asm volatile("s_waitcnt vmcnt(0) lgkmcnt(0)" ::: "memory");
    __syncthreads();
    if (threadIdx.x == 0) {
        int target = bi * 16 + 15;
        int g = (int)(blockIdx.x >> 4);
        int v = __hip_atomic_fetch_add(&bar[g * 16], 1, __ATOMIC_RELAXED, __HIP_MEMORY_SCOPE_AGENT);
        if (v == target) {
            int r = __hip_atomic_fetch_add(&bar[260], 1, __ATOMIC_RELAXED, __HIP_MEMORY_SCOPE_AGENT);
            if (r == target)
                __hip_atomic_store(&bar[276], bi + 1, __ATOMIC_RELAXED, __HIP_MEMORY_SCOPE_AGENT);
        }
        while (__hip_atomic_load(&bar[276], __ATOMIC_RELAXED, __HIP_MEMORY_SCOPE_AGENT) <= bi)
            __builtin_amdgcn_s_sleep(4);
    }
    __syncthreads();
}

// ---- fused [W update] + base+decayed matvec over K (phases B/C/D-workers) ----
// One memory round trip for all staging: (k,chunk) split over 512 threads.
__device__ __forceinline__ void fwd2phase(int bblk, int tid, int w, int lane, float* SM,
        const float* zinTP, const float* zinTQ, const float* bin,
        float* W, int Nout, float* zoutTP, float* zoutTQ,
        const float* uprev, const float* vprev, float* bl, bool upd) {
    vf4* s4 = (vf4*)SM;                 // [1024] vf4 reduce area
    float* hP8   = SM + 6144;           // [64][8]
    float* hQ8   = SM + 6656;           // [64][8]
    float* biasL = SM + 7168;           // [64]
    float* usL   = SM + 7232;           // [64]
    float* hsL   = SM + 7296;           // [64]
    float* hqL   = SM + 7360;           // [64]
    int p = bblk & 31, g = bblk >> 5;
    int kb = p * 64;
    int kk = tid >> 3, ch = tid & 7;
    int c0 = g * 256 + lane * 4;
    bool hasQ = (zinTQ != nullptr);

    vf4 zp = ld4_nw(zinTP + (size_t)(kb + kk) * 32 + ch * 4);
    vf4 zq;
    if (hasQ) zq = ld4_nw(zinTQ + (size_t)(kb + kk) * 32 + ch * 4);
    vf4 bi4; if (tid < 16) bi4 = ld4_nw(bin + kb + tid * 4);
    vf4 uu4; if (upd && tid >= 16 && tid < 32) uu4 = ld4_nw(uprev + kb + (tid - 16) * 4);
    vf4 vpv; if (upd) vpv = ld4_nw(vprev + c0);
    vmwait();
    PIN(zp); if (hasQ) PIN(zq);
    if (tid < 16) PIN(bi4);
    if (upd && tid >= 16 && tid < 32) PIN(uu4);
    if (upd) PIN(vpv);

    hP8[kk * 8 + ch] = sum4(zp);
    if (hasQ) hQ8[kk * 8 + ch] = sum4(zq);
    if (tid < 16) *(vf4*)(biasL + tid * 4) = bi4;
    if (upd && tid >= 16 && tid < 32) *(vf4*)(usL + (tid - 16) * 4) = LRC * uu4;
    __syncthreads();
    if (tid < 64) {
        float s = 0.f;
#pragma unroll
        for (int c = 0; c < 8; ++c) s += hP8[tid * 8 + c];
        float bv = biasL[tid];
        float h = fmaxf(s + bv, 0.f);
        float hq;
        if (hasQ) {
            float sq = 0.f;
#pragma unroll
            for (int c = 0; c < 8; ++c) sq += hQ8[tid * 8 + c];
            hq = fmaxf(DEC * (sq + bv), 0.f);
        } else {
            hq = DEC * h;
        }
        hsL[tid] = h; hqL[tid] = hq;
    }
    __syncthreads();

    vf4 ap = {0.f, 0.f, 0.f, 0.f};
    vf4 aq = {0.f, 0.f, 0.f, 0.f};
    if (upd) {
#pragma unroll
        for (int r = 0; r < 8; ++r) {
            int k2 = w * 8 + r;
            float* wp = W + (size_t)(p * 64 + k2) * Nout + c0;
            vf4 wv = *(const vf4*)wp;            // cached (own line)
            wv = DEC * wv - usL[k2] * vpv;
            st_cv4(wp, wv);                      // write-through
            ap += hsL[k2] * wv; aq += hqL[k2] * wv;
        }
    } else {
#pragma unroll
        for (int r = 0; r < 8; ++r) {
            int k2 = w * 8 + r;
            const vf4 wv = *(const vf4*)(W + (size_t)(p * 64 + k2) * Nout + c0);
            ap += hsL[k2] * wv; aq += hqL[k2] * wv;
        }
    }
    if (upd && bblk == 0) {
        int c = tid * 4;
        if (c < Nout) {
            vf4 dq = ld4_cv(vprev + c);
            vf4 bv = ld4_cv(bl + c);
            st_cv4(bl + c, DEC * bv - LRC * dq);
        }
    }
    s4[w * 64 + lane] = ap;
    s4[512 + w * 64 + lane] = aq;
    __syncthreads();
    if (w == 0) {
        vf4 sp = s4[lane], sq4 = s4[512 + lane];
#pragma unroll
        for (int q = 1; q < 8; ++q) { sp += s4[q * 64 + lane]; sq4 += s4[512 + q * 64 + lane]; }
        st_cv(zoutTP + (size_t)(c0 + 0) * 32 + p, sp.x);
        st_cv(zoutTP + (size_t)(c0 + 1) * 32 + p, sp.y);
        st_cv(zoutTP + (size_t)(c0 + 2) * 32 + p, sp.z);
        st_cv(zoutTP + (size_t)(c0 + 3) * 32 + p, sp.w);
        st_cv(zoutTQ + (size_t)(c0 + 0) * 32 + p, sq4.x);
        st_cv(zoutTQ + (size_t)(c0 + 1) * 32 + p, sq4.y);
        st_cv(zoutTQ + (size_t)(c0 + 2) * 32 + p, sq4.z);
        st_cv(zoutTQ + (size_t)(c0 + 3) * 32 + p, sq4.w);
    }
}

// ---- W^T backward (F/G): one batched round trip for delta+rows+gates ----
__device__ __forceinline__ void bwdphase(int bblk, int tid, int w, int lane,
        float* SM, float* sqw, const float* W,
        const float* dinP, const float* dinQ,
        const float* hP, const float* hQ,
        float* doutP, float* doutQ, float* slot) {
    float* dsP = SM; float* dsQ = SM + 2048;
    int k4 = tid * 4;
    vf4 vP = ld4_nw(dinP + k4);
    vf4 vQ = ld4_nw(dinQ + k4);
    int j = bblk * 8 + w;
    vf4 r[8];
    ldrow_nw(W + (size_t)j * 2048 + lane * 4, r);
    float gP, gQ;
    if (lane == 0) { gP = ld_nw(hP + j); gQ = ld_nw(hQ + j); }
    vmwait();
    PIN(vP); PIN(vQ);
#pragma unroll
    for (int i = 0; i < 8; ++i) PIN(r[i]);
    if (lane == 0) { PIN(gP); PIN(gQ); }
    *(vf4*)(dsP + k4) = vP;
    *(vf4*)(dsQ + k4) = vQ;
    __syncthreads();
    float ap = 0.f, aq = 0.f;
#pragma unroll
    for (int i = 0; i < 8; ++i) {
        int k0 = lane * 4 + i * 256;
        vf4 wv = r[i];
        ap += wv.x * dsP[k0] + wv.y * dsP[k0 + 1] + wv.z * dsP[k0 + 2] + wv.w * dsP[k0 + 3];
        aq += wv.x * dsQ[k0] + wv.y * dsQ[k0 + 1] + wv.z * dsQ[k0 + 2] + wv.w * dsQ[k0 + 3];
    }
#pragma unroll
    for (int off = 32; off > 0; off >>= 1) {
        ap += __shfl_down(ap, off);
        aq += __shfl_down(aq, off);
    }
    if (lane == 0) {
        float dp = (gP > 0.f) ? ap : 0.f;
        float dq = (gQ > 0.f) ? DEC * aq : 0.f;
        st_cv(doutP + j, dp); st_cv(doutQ + j, dq); sqw[w] = dp * dp;
    }
    __syncthreads();
    if (tid == 0) {
        float t = 0.f;
#pragma unroll
        for (int q = 0; q < 8; ++q) t += sqw[q];
        st_cv(slot + bblk, t);
    }
}

// ---------------- persistent TTT kernel ----------------
__global__ __launch_bounds__(512, 2) void k_ttt(const float* __restrict__ x,
        float* __restrict__ W1, float* __restrict__ b1,
        float* __restrict__ W2, float* __restrict__ b2,
        float* __restrict__ W3, float* __restrict__ b3,
        float* __restrict__ W4, float* __restrict__ b4,
        float* __restrict__ wsf, const int* __restrict__ flag, int* __restrict__ bar) {
    if (*flag == 0) return;
    const int b = blockIdx.x, tid = threadIdx.x;
    const int w = tid >> 6, lane = tid & 63;
    __shared__ float SM[14592];     // ~58 KB aliased per phase
    __shared__ float cnd[12];
    __shared__ float sqw[8];
    int bi = 0;

    for (int s = 0; s < 1024; ++s) {
        const float* xt = x + (size_t)s * 3072;
        const float* xp = x + (size_t)(s > 0 ? s - 1 : 0) * 3072;
        float* h3q_cur = wsf + ((s & 1) ? OFF_H3Q1 : OFF_H3Q0);
        const float* h3q_prev = wsf + ((s & 1) ? OFF_H3Q0 : OFF_H3Q1);
        float cond = 0.f;

        // ===== phase A: cond + fused W1/b1 update + z1 partials =====
        {
            vf4* s4 = (vf4*)SM;
            int g = b >> 5, p = b & 31;
            int c0 = g * 256 + lane * 4;
            int kb = p * 24 + w * 3;
            vf4 wv0 = *(const vf4*)(W1 + (size_t)(kb + 0) * 2048 + c0);
            vf4 wv1 = *(const vf4*)(W1 + (size_t)(kb + 1) * 2048 + c0);
            vf4 wv2 = *(const vf4*)(W1 + (size_t)(kb + 2) * 2048 + c0);
            float a0 = xt[kb + 0], a1 = xt[kb + 1], a2 = xt[kb + 2];
            vf4 dv = {0.f, 0.f, 0.f, 0.f};
            float u0 = 0.f, u1 = 0.f, u2 = 0.f;
            if (s > 0) {
                dv = ld4_nw(wsf + OFF_D1Q + c0);
                vf4 sl4;
                if (w < 3) {
                    const float* sl = wsf + (w == 0 ? OFF_SL1 : (w == 1 ? OFF_SL2 : OFF_SL3));
                    sl4 = ld4_nw(sl + lane * 4);
                }
                float nv;
                if (w == 3 && lane < 6)
                    nv = ld_nw(lane < 5 ? (wsf + OFF_NSQ + lane) : (wsf + OFF_BUF + ((s - 1) & 1)));
                vmwait();
                PIN(dv);
                if (w < 3) PIN(sl4);
                if (w == 3 && lane < 6) PIN(nv);
                u0 = LRC * xp[kb + 0]; u1 = LRC * xp[kb + 1]; u2 = LRC * xp[kb + 2];
                if (w < 3) {
                    float v = sum4(sl4);
#pragma unroll
                    for (int off = 32; off > 0; off >>= 1) v += __shfl_down(v, off);
                    if (lane == 0) cnd[w] = v;
                } else if (w == 3 && lane < 6) {
                    cnd[3 + lane] = nv;
                }
                __syncthreads();
                float nd1 = sqrtf(cnd[0]), nd2 = sqrtf(cnd[1]), nd3 = sqrtf(cnd[2]);
                float nx = sqrtf(cnd[3]), nh1 = sqrtf(cnd[4]), nh2 = sqrtf(cnd[5]);
                float nh3 = sqrtf(cnd[6]), nd4 = sqrtf(cnd[7]);
                float bufold = cnd[8];
                float surprise = nx * nd1 + nd1 + nh1 * nd2 + nd2 + nh2 * nd3 + nd3 + nh3 * nd4 + nd4;
                float bufnew = (s == 1) ? surprise : (0.9f * bufold + 0.1f * surprise);
                cond = (bufnew > 0.1f) ? 1.f : 0.f;
                if (b == 0 && tid == 0) {
                    st_cv(wsf + OFF_BUF + (s & 1), bufnew);
                    st_cv(wsf + OFF_CONDF, cond);
                }
            } else {
                if (b == 0 && tid == 0) st_cv(wsf + OFF_CONDF, 0.f);
            }
            if (cond != 0.f) {
                wv0 = DEC * wv0 - u0 * dv;
                wv1 = DEC * wv1 - u1 * dv;
                wv2 = DEC * wv2 - u2 * dv;
                st_cv4(W1 + (size_t)(kb + 0) * 2048 + c0, wv0);
                st_cv4(W1 + (size_t)(kb + 1) * 2048 + c0, wv1);
                st_cv4(W1 + (size_t)(kb + 2) * 2048 + c0, wv2);
                if (b == 0) {
                    int c = tid * 4;
                    vf4 dq = ld4_cv(wsf + OFF_D1Q + c);
                    vf4 bv = ld4_cv(b1 + c);
                    st_cv4(b1 + c, DEC * bv - LRC * dq);
                }
            }
            vf4 acc = a0 * wv0 + a1 * wv1 + a2 * wv2;
            s4[w * 64 + lane] = acc;
            __syncthreads();
            if (w == 0) {
                vf4 t = s4[lane];
#pragma unroll
                for (int q = 1; q < 8; ++q) t += s4[q * 64 + lane];
                st_cv(wsf + OFF_Z1T + (size_t)(c0 + 0) * 32 + p, t.x);
                st_cv(wsf + OFF_Z1T + (size_t)(c0 + 1) * 32 + p, t.y);
                st_cv(wsf + OFF_Z1T + (size_t)(c0 + 2) * 32 + p, t.z);
                st_cv(wsf + OFF_Z1T + (size_t)(c0 + 3) * 32 + p, t.w);
            }
        }
        gbar(bar, bi++);
        bool upd = (cond != 0.f);

        // ===== phase B: layer 2 =====
        fwd2phase(b, tid, w, lane, SM, wsf + OFF_Z1T, nullptr, b1, W2, 2048,
                  wsf + OFF_Z2TP, wsf + OFF_Z2TQ, wsf + OFF_H1Q, wsf + OFF_D2Q, b2, upd);
        gbar(bar, bi++);

        // ===== phase C: layer 3 =====
        fwd2phase(b, tid, w, lane, SM, wsf + OFF_Z2TP, wsf + OFF_Z2TQ, b2, W3, 2048,
                  wsf + OFF_Z3TP, wsf + OFF_Z3TQ, wsf + OFF_H2Q, wsf + OFF_D3Q, b3, upd);
        gbar(bar, bi++);

        // ===== phase D: layer 4 (96 blocks) + h finalize/norms (spares) =====
        if (b < 96) {
            fwd2phase(b, tid, w, lane, SM, wsf + OFF_Z3TP, wsf + OFF_Z3TQ, b3, W4, 768,
                      wsf + OFF_Z4TP, wsf + OFF_Z4TQ, h3q_prev, wsf + OFF_D4Q, b4, upd);
        } else {
            int idx = b - 96;
            float* partP = SM;            // [128][4]
            float* partQ = SM + 512;      // [128][4]
            float* biasD = SM + 1024;     // [128]
            if (idx < 16) {
                int base = idx * 128, el = tid >> 2, c2 = tid & 3;
                const float* zl = wsf + OFF_Z1T + (size_t)(base + el) * 32 + c2 * 8;
                vf4 za = ld4_nw(zl), zb = ld4_nw(zl + 4);
                vf4 bb; if (tid < 32) bb = ld4_nw(b1 + base + tid * 4);
                vmwait(); PIN(za); PIN(zb); if (tid < 32) PIN(bb);
                partP[el * 4 + c2] = sum4(za) + sum4(zb);
                if (tid < 32) *(vf4*)(biasD + tid * 4) = bb;
                __syncthreads();
                if (tid < 128) {
                    float sv = partP[tid * 4] + partP[tid * 4 + 1] + partP[tid * 4 + 2] + partP[tid * 4 + 3];
                    float h = fmaxf(sv + biasD[tid], 0.f);
                    st_cv(wsf + OFF_H1F + base + tid, h);
                    st_cv(wsf + OFF_H1Q + base + tid, DEC * h);
                }
            } else if (idx < 48) {
                int l3 = (idx >= 32);
                int base = (idx - (l3 ? 32 : 16)) * 128, el = tid >> 2, c2 = tid & 3;
                const float* ZP = wsf + (l3 ? OFF_Z3TP : OFF_Z2TP);
                const float* ZQ = wsf + (l3 ? OFF_Z3TQ : OFF_Z2TQ);
                const float* bb_ = l3 ? b3 : b2;
                const float* zp0 = ZP + (size_t)(base + el) * 32 + c2 * 8;
                const float* zq0 = ZQ + (size_t)(base + el) * 32 + c2 * 8;
                vf4 pa = ld4_nw(zp0), pb = ld4_nw(zp0 + 4);
                vf4 qa = ld4_nw(zq0), qb = ld4_nw(zq0 + 4);
                vf4 bb; if (tid < 32) bb = ld4_nw(bb_ + base + tid * 4);
                vmwait(); PIN(pa); PIN(pb); PIN(qa); PIN(qb); if (tid < 32) PIN(bb);
                partP[el * 4 + c2] = sum4(pa) + sum4(pb);
                partQ[el * 4 + c2] = sum4(qa) + sum4(qb);
                if (tid < 32) *(vf4*)(biasD + tid * 4) = bb;
                __syncthreads();
                if (tid < 128) {
                    float sp = partP[tid * 4] + partP[tid * 4 + 1] + partP[tid * 4 + 2] + partP[tid * 4 + 3];
                    float sq = partQ[tid * 4] + partQ[tid * 4 + 1] + partQ[tid * 4 + 2] + partQ[tid * 4 + 3];
                    float bv = biasD[tid];
                    if (l3) {
                        st_cv(wsf + OFF_H3F + base + tid, fmaxf(sp + bv, 0.f));
                        st_cv(h3q_cur + base + tid, fmaxf(DEC * (sq + bv), 0.f));
                    } else {
                        st_cv(wsf + OFF_H2F + base + tid, fmaxf(sp + bv, 0.f));
                        st_cv(wsf + OFF_H2Q + base + tid, fmaxf(DEC * (sq + bv), 0.f));
                    }
                }
            } else if (idx == 48) {          // ||x||^2 (x is read-only: cached)
                float v = 0.f;
                for (int e = tid; e < 768; e += 512) { float xv = xt[e]; v += xv * xv; }
                float t = block_reduce_512(v);
                if (tid == 0) st_cv(wsf + OFF_NSQ + 0, t);
            } else if (idx < 52) {           // ||h1||^2 / ||h2||^2 / ||h3||^2
                const float* ZT = (idx == 49) ? (wsf + OFF_Z1T) : (idx == 50 ? (wsf + OFF_Z2TP) : (wsf + OFF_Z3TP));
                const float* bb_ = (idx == 49) ? b1 : (idx == 50 ? b2 : b3);
                int nk = idx - 48;
                float acc = 0.f;
#pragma unroll
                for (int pass = 0; pass < 4; ++pass) {
                    int e = pass * 512 + tid;
                    const float* zl = ZT + (size_t)e * 32;
                    vf4 z0 = ld4_nw(zl), z1 = ld4_nw(zl + 4), z2 = ld4_nw(zl + 8), z3 = ld4_nw(zl + 12);
                    vf4 z4 = ld4_nw(zl + 16), z5 = ld4_nw(zl + 20), z6 = ld4_nw(zl + 24), z7 = ld4_nw(zl + 28);
                    float bv = ld_nw(bb_ + e);
                    vmwait();
                    PIN(z0); PIN(z1); PIN(z2); PIN(z3); PIN(z4); PIN(z5); PIN(z6); PIN(z7); PIN(bv);
                    float sv = sum4(z0) + sum4(z1) + sum4(z2) + sum4(z3)
                             + sum4(z4) + sum4(z5) + sum4(z6) + sum4(z7);
                    float h = fmaxf(sv + bv, 0.f);
                    acc += h * h;
                }
                float t = block_reduce_512(acc);
                if (tid == 0) st_cv(wsf + OFF_NSQ + nk, t);
            }
        }
        gbar(bar, bi++);

        // ===== phase E: bwd L4 (parallel d4 rebuild, 2 round trips) =====
        {
            float* partP = SM;            // [768][8]
            float* partQ = SM + 6144;     // [768][8]
            float* d4P   = SM + 12288;    // [768]
            float* d4Q   = SM + 13056;    // [768]
            float* biasE = SM + 13824;    // [768]
            int er = tid >> 3, ch = tid & 7;
            // batch 1: P partials + bias
            vf4 pv[12];
#pragma unroll
            for (int i = 0; i < 12; ++i)
                pv[i] = ld4_nw(wsf + OFF_Z4TP + (size_t)(i * 64 + er) * 32 + ch * 4);
            vf4 b4v; if (tid < 192) b4v = ld4_nw(b4 + tid * 4);
            vmwait();
#pragma unroll
            for (int i = 0; i < 12; ++i) PIN(pv[i]);
            if (tid < 192) PIN(b4v);
#pragma unroll
            for (int i = 0; i < 12; ++i) partP[(size_t)(i * 64 + er) * 8 + ch] = sum4(pv[i]);
            if (tid < 192) *(vf4*)(biasE + tid * 4) = b4v;
            // batch 2: Q partials + W4 rows + gates
            vf4 qv[12];
#pragma unroll
            for (int i = 0; i < 12; ++i)
                qv[i] = ld4_nw(wsf + OFF_Z4TQ + (size_t)(i * 64 + er) * 32 + ch * 4);
            int j = b * 8 + w;
            vf4 r0, r1, r2;
            ldrow3_nw(W4 + (size_t)j * 768 + lane * 4, r0, r1, r2);
            float gP, gQ;
            if (lane == 0) { gP = ld_nw(wsf + OFF_H3F + j); gQ = ld_nw(h3q_cur + j); }
            vmwait();
#pragma unroll
            for (int i = 0; i < 12; ++i) PIN(qv[i]);
            PIN(r0); PIN(r1); PIN(r2);
            if (lane == 0) { PIN(gP); PIN(gQ); }
#pragma unroll
            for (int i = 0; i < 12; ++i) partQ[(size_t)(i * 64 + er) * 8 + ch] = sum4(qv[i]);
            __syncthreads();
            if (tid < 256) {
#pragma unroll
                for (int m = 0; m < 3; ++m) {
                    int e = tid + m * 256;
                    float sp = 0.f, sq = 0.f;
#pragma unroll
                    for (int c = 0; c < 8; ++c) { sp += partP[e * 8 + c]; sq += partQ[e * 8 + c]; }
                    float bv = biasE[e], tv = xt[e];
                    d4P[e] = 2.f * ((sp + bv) - tv) * (1.f / 768.f);
                    d4Q[e] = 2.f * (DEC * (sq + bv) - tv) * (1.f / 768.f);
                }
            }
            __syncthreads();
            float ap = 0.f, aq = 0.f;
            {
                int k0 = lane * 4;
                ap += r0.x * d4P[k0] + r0.y * d4P[k0 + 1] + r0.z * d4P[k0 + 2] + r0.w * d4P[k0 + 3];
                aq += r0.x * d4Q[k0] + r0.y * d4Q[k0 + 1] + r0.z * d4Q[k0 + 2] + r0.w * d4Q[k0 + 3];
                k0 += 256;
                ap += r1.x * d4P[k0] + r1.y * d4P[k0 + 1] + r1.z * d4P[k0 + 2] + r1.w * d4P[k0 + 3];
                aq += r1.x * d4Q[k0] + r1.y * d4Q[k0 + 1] + r1.z * d4Q[k0 + 2] + r1.w * d4Q[k0 + 3];
                k0 += 256;
                ap += r2.x * d4P[k0] + r2.y * d4P[k0 + 1] + r2.z * d4P[k0 + 2] + r2.w * d4P[k0 + 3];
                aq += r2.x * d4Q[k0] + r2.y * d4Q[k0 + 1] + r2.z * d4Q[k0 + 2] + r2.w * d4Q[k0 + 3];
            }
#pragma unroll
            for (int off = 32; off > 0; off >>= 1) {
                ap += __shfl_down(ap, off);
                aq += __shfl_down(aq, off);
            }
            if (lane == 0) {
                float dp = (gP > 0.f) ? ap : 0.f;
                float dq = (gQ > 0.f) ? DEC * aq : 0.f;
                st_cv(wsf + OFF_D3F + j, dp); st_cv(wsf + OFF_D3Q + j, dq); sqw[w] = dp * dp;
            }
            __syncthreads();
            if (tid == 0) {
                float t = 0.f;
#pragma unroll
                for (int q = 0; q < 8; ++q) t += sqw[q];
                st_cv(wsf + OFF_SL3 + b, t);
            }
            if (b == 0) {
                float v = 0.f;
                for (int e = tid; e < 768; e += 512) {
                    st_cv(wsf + OFF_D4F + e, d4P[e]);
                    st_cv(wsf + OFF_D4Q + e, d4Q[e]);
                    v += d4P[e] * d4P[e];
                }
                float t = block_reduce_512(v);
                if (tid == 0) st_cv(wsf + OFF_NSQ + 4, t);
            }
        }
        gbar(bar, bi++);

        // ===== phase F: bwd L3 =====
        bwdphase(b, tid, w, lane, SM, sqw, W3,
                 wsf + OFF_D3F, wsf + OFF_D3Q, wsf + OFF_H2F, wsf + OFF_H2Q,
                 wsf + OFF_D2F, wsf + OFF_D2Q, wsf + OFF_SL2);
        gbar(bar, bi++);

        // ===== phase G: bwd L2 =====
        bwdphase(b, tid, w, lane, SM, sqw, W2,
                 wsf + OFF_D2F, wsf + OFF_D2Q, wsf + OFF_H1F, wsf + OFF_H1Q,
                 wsf + OFF_D1F, wsf + OFF_D1Q, wsf + OFF_SL1);
        gbar(bar, bi++);
    }
}

// ---------- post-loop: apply the LAST step's update once ----------
__global__ __launch_bounds__(512) void k_upd(int step, float* __restrict__ wsf,
                                             float* __restrict__ W1, float* __restrict__ b1,
                                             float* __restrict__ W2, float* __restrict__ b2,
                                             float* __restrict__ W3, float* __restrict__ b3,
                                             float* __restrict__ W4, float* __restrict__ b4,
                                             const float* __restrict__ xt,
                                             const int* __restrict__ flag) {
    if (*flag == 0) return;
    int tid = threadIdx.x, b = blockIdx.x;
    float s3 = block_reduce_512((tid < 256) ? wsf[OFF_SL3 + tid] : 0.f);
    float s2 = block_reduce_512((tid < 256) ? wsf[OFF_SL2 + tid] : 0.f);
    float s1 = block_reduce_512((tid < 256) ? wsf[OFF_SL1 + tid] : 0.f);
    __shared__ float condsh;
    if (tid == 0) {
        float nx = sqrtf(wsf[OFF_NSQ + 0]);
        float nh1 = sqrtf(wsf[OFF_NSQ + 1]);
        float nh2 = sqrtf(wsf[OFF_NSQ + 2]);
        float nh3 = sqrtf(wsf[OFF_NSQ + 3]);
        float nd4 = sqrtf(wsf[OFF_NSQ + 4]);
        float nd3 = sqrtf(s3), nd2 = sqrtf(s2), nd1 = sqrtf(s1);
        float surprise = nx * nd1 + nd1 + nh1 * nd2 + nd2 + nh2 * nd3 + nd3 + nh3 * nd4 + nd4;
        float bufold = wsf[OFF_BUF + (step & 1)];
        float bufnew = (step == 0) ? surprise : (0.9f * bufold + 0.1f * surprise);
        condsh = (bufnew > 0.1f) ? 1.f : 0.f;
    }
    __syncthreads();
    if (condsh == 0.f) return;

    const float* d1q = wsf + OFF_D1Q;
    const float* d2q = wsf + OFF_D2Q;
    const float* d3q = wsf + OFF_D3Q;
    const float* d4q = wsf + OFF_D4Q;
    const float* h1q = wsf + OFF_H1Q;
    const float* h2q = wsf + OFF_H2Q;
    const float* h3q = wsf + OFF_H3Q1;   // step 1023 is odd -> buffer 1
    int c = tid * 4;
    {
        float4 dv = *(const float4*)(d1q + c);
#pragma unroll
        for (int r = 0; r < 3; ++r) {
            int i = b * 3 + r;
            float u = LRC * xt[i];
            float4* wp = (float4*)(W1 + (size_t)i * 2048 + c);
            float4 wv = *wp;
            wv.x = DEC * wv.x - u * dv.x; wv.y = DEC * wv.y - u * dv.y;
            wv.z = DEC * wv.z - u * dv.z; wv.w = DEC * wv.w - u * dv.w;
            *wp = wv;
        }
    }
    {
        float4 dv = *(const float4*)(d2q + c);
#pragma unroll
        for (int r = 0; r < 8; ++r) {
            int i = b * 8 + r;
            float u = LRC * h1q[i];
            float4* wp = (float4*)(W2 + (size_t)i * 2048 + c);
            float4 wv = *wp;
            wv.x = DEC * wv.x - u * dv.x; wv.y = DEC * wv.y - u * dv.y;
            wv.z = DEC * wv.z - u * dv.z; wv.w = DEC * wv.w - u * dv.w;
            *wp = wv;
        }
    }
    {
        float4 dv = *(const float4*)(d3q + c);
#pragma unroll
        for (int r = 0; r < 8; ++r) {
            int i = b * 8 + r;
            float u = LRC * h2q[i];
            float4* wp = (float4*)(W3 + (size_t)i * 2048 + c);
            float4 wv = *wp;
            wv.x = DEC * wv.x - u * dv.x; wv.y = DEC * wv.y - u * dv.y;
            wv.z = DEC * wv.z - u * dv.z; wv.w = DEC * wv.w - u * dv.w;
            *wp = wv;
        }
    }
    if (tid < 192) {
        float4 dv = *(const float4*)(d4q + c);
#pragma unroll
        for (int r = 0; r < 8; ++r) {
            int i = b * 8 + r;
            float u = LRC * h3q[i];
            float4* wp = (float4*)(W4 + (size_t)i * 768 + c);
            float4 wv = *wp;
            wv.x = DEC * wv.x - u * dv.x; wv.y = DEC * wv.y - u * dv.y;
            wv.z = DEC * wv.z - u * dv.z; wv.w = DEC * wv.w - u * dv.w;
            *wp = wv;
        }
    }
    if (b == 0) {
        float4 dv = *(const float4*)(d1q + c);
        float4* bp = (float4*)(b1 + c);
        float4 bv = *bp;
        bv.x = DEC * bv.x - LRC * dv.x; bv.y = DEC * bv.y - LRC * dv.y;
        bv.z = DEC * bv.z - LRC * dv.z; bv.w = DEC * bv.w - LRC * dv.w;
        *bp = bv;
    } else if (b == 1) {
        float4 dv = *(const float4*)(d2q + c);
        float4* bp = (float4*)(b2 + c);
        float4 bv = *bp;
        bv.x = DEC * bv.x - LRC * dv.x; bv.y = DEC * bv.y - LRC * dv.y;
        bv.z = DEC * bv.z - LRC * dv.z; bv.w = DEC * bv.w - LRC * dv.w;
        *bp = bv;
    } else if (b == 2) {
        float4 dv = *(const float4*)(d3q + c);
        float4* bp = (float4*)(b3 + c);
        float4 bv = *bp;
        bv.x = DEC * bv.x - LRC * dv.x; bv.y = DEC * bv.y - LRC * dv.y;
        bv.z = DEC * bv.z - LRC * dv.z; bv.w = DEC * bv.w - LRC * dv.w;
        *bp = bv;
    } else if (b == 3 && tid < 192) {
        float4 dv = *(const float4*)(d4q + c);
        float4* bp = (float4*)(b4 + c);
        float4 bv = *bp;
        bv.x = DEC * bv.x - LRC * dv.x; bv.y = DEC * bv.y - LRC * dv.y;
        bv.z = DEC * bv.z - LRC * dv.z; bv.w = DEC * bv.w - LRC * dv.w;
        *bp = bv;
    }
}

// ---------- final batch forward: fp32 tiled GEMM C = act(A@W + bias) ----------
__global__ __launch_bounds__(256) void k_gemm(const float* __restrict__ A,
                                              const float* __restrict__ W,
                                              const float* __restrict__ bias,
                                              float* __restrict__ C,
                                              int M, int N, int K, int do_relu) {
    __shared__ float sA[16][64];
    __shared__ float sB[16][128];
    int bn = blockIdx.x, bm = blockIdx.y;
    int m0 = bm * 64, n0 = bn * 128;
    int tid = threadIdx.x;
    int tx = tid & 31, ty = tid >> 5;
    float acc[8][4];
#pragma unroll
    for (int i = 0; i < 8; ++i)
#pragma unroll
        for (int j = 0; j < 4; ++j) acc[i][j] = 0.f;

    for (int kt = 0; kt < K; kt += 16) {
        {
            int r = tid >> 2, cc = (tid & 3) * 4;
            const float4 a4 = *(const float4*)(A + (size_t)(m0 + r) * K + kt + cc);
            sA[cc + 0][r] = a4.x; sA[cc + 1][r] = a4.y; sA[cc + 2][r] = a4.z; sA[cc + 3][r] = a4.w;
        }
        {
            int r = tid >> 5, cc = (tid & 31) * 4;
            *(float4*)(&sB[r][cc]) = *(const float4*)(W + (size_t)(kt + r) * N + n0 + cc);
            *(float4*)(&sB[r + 8][cc]) = *(const float4*)(W + (size_t)(kt + r + 8) * N + n0 + cc);
        }
        __syncthreads();
#pragma unroll
        for (int k = 0; k < 16; ++k) {
            float av[8];
#pragma unroll
            for (int i = 0; i < 8; ++i) av[i] = sA[k][ty * 8 + i];
            float bx = sB[k][tx * 4 + 0], by = sB[k][tx * 4 + 1];
            float bz = sB[k][tx * 4 + 2], bw = sB[k][tx * 4 + 3];
#pragma unroll
            for (int i = 0; i < 8; ++i) {
                acc[i][0] += av[i] * bx; acc[i][1] += av[i] * by;
                acc[i][2] += av[i] * bz; acc[i][3] += av[i] * bw;
            }
        }
        __syncthreads();
    }
    float bx = bias[n0 + tx * 4 + 0], by = bias[n0 + tx * 4 + 1];
    float bz = bias[n0 + tx * 4 + 2], bw = bias[n0 + tx * 4 + 3];
#pragma unroll
    for (int i = 0; i < 8; ++i) {
        int m = m0 + ty * 8 + i;
        float4 v;
        v.x = acc[i][0] + bx; v.y = acc[i][1] + by;
        v.z = acc[i][2] + bz; v.w = acc[i][3] + bw;
        if (do_relu) {
            v.x = fmaxf(v.x, 0.f); v.y = fmaxf(v.y, 0.f);
            v.z = fmaxf(v.z, 0.f); v.w = fmaxf(v.w, 0.f);
        }
        *(float4*)(C + (size_t)m * N + n0 + tx * 4) = v;
    }
}

__global__ __launch_bounds__(128) void k_colsum(const float* __restrict__ Y,
                                                float* __restrict__ out) {
    int c = blockIdx.x * 128 + threadIdx.x;
    int r0 = blockIdx.y * 128;
    float s = 0.f;
    for (int r = 0; r < 128; ++r) s += Y[(size_t)(r0 + r) * 768 + c];
    out[blockIdx.y * 768 + c] = s;
}

__global__ __launch_bounds__(768) void k_out(const float* __restrict__ msum,
                                             float* __restrict__ out) {
    int c = threadIdx.x;
    float s = 0.f;
#pragma unroll
    for (int i = 0; i < 32; ++i) s += msum[i * 768 + c];
    out[c] = s * (1.f / 4096.f);
}

extern "C" void kernel_launch(void* const* d_in, const int* in_sizes, int n_in,
                              void* d_out, int out_size, void* d_ws, size_t ws_size,
                              hipStream_t stream) {
    const float* x = (const float*)d_in[0];
    float* W1 = (float*)d_in[1];
    float* b1 = (float*)d_in[2];
    float* W2 = (float*)d_in[3];
    float* b2 = (float*)d_in[4];
    float* W3 = (float*)d_in[5];
    float* b3 = (float*)d_in[6];
    float* W4 = (float*)d_in[7];
    float* b4 = (float*)d_in[8];
    const int* flag = (const int*)d_in[9];
    float* wsf = (float*)d_ws;
    int* bar = (int*)(wsf + OFF_BAR);

    hipMemsetAsync((void*)bar, 0, 1024 * sizeof(int), stream);

    void* args[] = {(void*)&x, (void*)&W1, (void*)&b1, (void*)&W2, (void*)&b2,
                    (void*)&W3, (void*)&b3, (void*)&W4, (void*)&b4,
                    (void*)&wsf, (void*)&flag, (void*)&bar};
    hipLaunchCooperativeKernel((void*)k_ttt, dim3(256), dim3(512), args, 0, stream);

    k_upd<<<256, 512, 0, stream>>>(1023, wsf, W1, b1, W2, b2, W3, b3, W4, b4,
                                   x + (size_t)1023 * 4 * 768, flag);

    float* HA = wsf + OFF_HA;
    float* HB = wsf + OFF_HB;
    for (int ch = 0; ch < 4; ++ch) {
        const float* Xc = x + (size_t)ch * 1024 * 768;
        k_gemm<<<dim3(16, 16), 256, 0, stream>>>(Xc, W1, b1, HA, 1024, 2048, 768, 1);
        k_gemm<<<dim3(16, 16), 256, 0, stream>>>(HA, W2, b2, HB, 1024, 2048, 2048, 1);
        k_gemm<<<dim3(16, 16), 256, 0, stream>>>(HB, W3, b3, HA, 1024, 2048, 2048, 1);
        k_gemm<<<dim3(6, 16), 256, 0, stream>>>(HA, W4, b4, HB, 1024, 768, 2048, 0);
        k_colsum<<<dim3(6, 8), 128, 0, stream>>>(HB, wsf + OFF_MSUM + (size_t)ch * 8 * 768);
    }
    k_out<<<1, 768, 0, stream>>>(wsf + OFF_MSUM, (float*)d_out);
}

// Round 7
// 69457.098 us; speedup vs baseline: 1.1168x; 1.1168x over previous
//
#include <hip/hip_runtime.h>
#include <cstddef>

#define LRC 0.001f
#define DEC 0.99f

typedef float vf4 __attribute__((ext_vector_type(4)));

// ---------------- workspace layout (float offsets) ----------------
static const size_t OFF_Z1T  = 0;           // [2048][32] transposed partials
static const size_t OFF_Z2TP = 65536;
static const size_t OFF_Z2TQ = 131072;
static const size_t OFF_Z3TP = 196608;
static const size_t OFF_Z3TQ = 262144;
static const size_t OFF_Z4TP = 327680;      // [768][32]
static const size_t OFF_Z4TQ = 352256;
static const size_t OFF_H1F = 376832;       // 2048
static const size_t OFF_H1Q0 = 378880;      // h1q slot0 (even steps)
static const size_t OFF_H2F = 380928;
static const size_t OFF_H2Q0 = 382976;
static const size_t OFF_H3F = 385024;
static const size_t OFF_H3Q0 = 387072;
static const size_t OFF_D4F = 389120;       // 768 (finalized d4 P)
static const size_t OFF_D3F = 390656;       // 2048
static const size_t OFF_D3Q0 = 392704;
static const size_t OFF_D2F = 394752;
static const size_t OFF_D2Q0 = 396800;
static const size_t OFF_D1F = 398848;
static const size_t OFF_D1Q = 400896;       // single buffer
static const size_t OFF_NSQ = 402944;       // [0]=x,[1]=h1,[2]=h2,[3]=h3,[4..6]=|d4|^2 parts
static const size_t OFF_SL3 = 402960;       // 256
static const size_t OFF_SL2 = 403216;
static const size_t OFF_SL1 = 403472;
static const size_t OFF_BUF = 403728;       // 2
static const size_t OFF_MSUM = 403732;      // [32][768]
static const size_t OFF_HA  = 428308;       // tail GEMM buffer; head carved during TTT:
static const size_t OFF_BAR  = OFF_HA;            // 1024 ints
static const size_t OFF_H3Q1 = OFF_HA + 1024;     // 2048
static const size_t OFF_H1Q1 = OFF_HA + 3072;     // 2048
static const size_t OFF_H2Q1 = OFF_HA + 5120;     // 2048
static const size_t OFF_D2Q1 = OFF_HA + 7168;     // 2048
static const size_t OFF_D3Q1 = OFF_HA + 9216;     // 2048
static const size_t OFF_D4Q0 = OFF_HA + 11264;    // 768
static const size_t OFF_D4Q1 = OFF_HA + 12032;    // 768
static const size_t OFF_HB  = 2525460;

// ---------------- MALL-coherent access (sc0 sc1 = bypass L1+L2) --------------
#define PIN(v) asm volatile("" : "+v"(v))
__device__ __forceinline__ void vmwait() { asm volatile("s_waitcnt vmcnt(0)" ::: "memory"); }
__device__ __forceinline__ float ld_nw(const float* p) {
    float v;
    asm volatile("global_load_dword %0, %1, off sc0 sc1" : "=&v"(v) : "v"(p) : "memory");
    return v;
}
__device__ __forceinline__ vf4 ld4_nw(const float* p) {
    vf4 v;
    asm volatile("global_load_dwordx4 %0, %1, off sc0 sc1" : "=&v"(v) : "v"(p) : "memory");
    return v;
}
__device__ __forceinline__ float ld_cv(const float* p) {
    float v = ld_nw(p); vmwait(); PIN(v); return v;
}
__device__ __forceinline__ vf4 ld4_cv(const float* p) {
    vf4 v = ld4_nw(p); vmwait(); PIN(v); return v;
}
__device__ __forceinline__ void st_cv(float* p, float v) {
    asm volatile("global_store_dword %0, %1, off sc0 sc1" :: "v"(p), "v"(v) : "memory");
}
__device__ __forceinline__ void st_cv4(float* p, vf4 v) {
    asm volatile("global_store_dwordx4 %0, %1, off sc0 sc1" :: "v"(p), "v"(v) : "memory");
}
__device__ __forceinline__ float sum4(vf4 v) { return v.x + v.y + v.z + v.w; }

__device__ float block_reduce_512(float v) {
    __shared__ float red[512];
    int t = threadIdx.x;
    red[t] = v;
    __syncthreads();
    for (int s = 256; s > 0; s >>= 1) {
        if (t < s) red[t] += red[t + s];
        __syncthreads();
    }
    float r = red[0];
    __syncthreads();
    return r;
}

// ---- fence-free grid barrier: RELAXED atomics only ----
__device__ inline void gbar(int* bar, int bi) {
    asm volatile("s_waitcnt vmcnt(0) lgkmcnt(0)" ::: "memory");
    __syncthreads();
    if (threadIdx.x == 0) {
        int target = bi * 16 + 15;
        int g = (int)(blockIdx.x >> 4);
        int v = __hip_atomic_fetch_add(&bar[g * 16], 1, __ATOMIC_RELAXED, __HIP_MEMORY_SCOPE_AGENT);
        if (v == target) {
            int r = __hip_atomic_fetch_add(&bar[260], 1, __ATOMIC_RELAXED, __HIP_MEMORY_SCOPE_AGENT);
            if (r == target)
                __hip_atomic_store(&bar[276], bi + 1, __ATOMIC_RELAXED, __HIP_MEMORY_SCOPE_AGENT);
        }
        while (__hip_atomic_load(&bar[276], __ATOMIC_RELAXED, __HIP_MEMORY_SCOPE_AGENT) <= bi)
            __builtin_amdgcn_s_sleep(4);
    }
    __syncthreads();
}

// ---- fused [W update] + base+decayed matvec over K=2048 slice --------------
// REG=true: weights in wreg[8] (updated in place). REG=false: memory RMW (sc1 store).
template<bool REGW>
__device__ __forceinline__ void fwd2phase(vf4* wreg, int bblk, int tid, int w, int lane, float* SM,
        const float* zinTP, const float* zinTQ, const float* bin,
        float* W, int Nout, float* zoutTP, float* zoutTQ,
        const float* uprev, const float* vprev, float* bl, bool upd) {
    vf4* s4 = (vf4*)SM;                 // [1024] vf4 reduce area (4096 floats)
    float* hP8   = SM + 4096;           // [64][8]
    float* hQ8   = SM + 4608;           // [64][8]
    float* biasL = SM + 5120;           // [64]
    float* usL   = SM + 5184;           // [64]
    float* hsL   = SM + 5248;           // [64]
    float* hqL   = SM + 5312;           // [64]
    int p = bblk & 31, g = bblk >> 5;
    int kb = p * 64;
    int kk = tid >> 3, ch = tid & 7;
    int c0 = g * 256 + lane * 4;
    bool hasQ = (zinTQ != nullptr);

    vf4 zp = ld4_nw(zinTP + (size_t)(kb + kk) * 32 + ch * 4);
    vf4 zq;
    if (hasQ) zq = ld4_nw(zinTQ + (size_t)(kb + kk) * 32 + ch * 4);
    vf4 bi4; if (tid < 16) bi4 = ld4_nw(bin + kb + tid * 4);
    vf4 uu4; if (upd && tid >= 16 && tid < 32) uu4 = ld4_nw(uprev + kb + (tid - 16) * 4);
    vf4 vpv; if (upd) vpv = ld4_nw(vprev + c0);
    vmwait();
    PIN(zp); if (hasQ) PIN(zq);
    if (tid < 16) PIN(bi4);
    if (upd && tid >= 16 && tid < 32) PIN(uu4);
    if (upd) PIN(vpv);

    hP8[kk * 8 + ch] = sum4(zp);
    if (hasQ) hQ8[kk * 8 + ch] = sum4(zq);
    if (tid < 16) *(vf4*)(biasL + tid * 4) = bi4;
    if (upd && tid >= 16 && tid < 32) *(vf4*)(usL + (tid - 16) * 4) = LRC * uu4;
    __syncthreads();
    if (tid < 64) {
        float s = 0.f;
#pragma unroll
        for (int c = 0; c < 8; ++c) s += hP8[tid * 8 + c];
        float bv = biasL[tid];
        float h = fmaxf(s + bv, 0.f);
        float hq;
        if (hasQ) {
            float sq = 0.f;
#pragma unroll
            for (int c = 0; c < 8; ++c) sq += hQ8[tid * 8 + c];
            hq = fmaxf(DEC * (sq + bv), 0.f);
        } else {
            hq = DEC * h;
        }
        hsL[tid] = h; hqL[tid] = hq;
    }
    __syncthreads();

    vf4 ap = {0.f, 0.f, 0.f, 0.f};
    vf4 aq = {0.f, 0.f, 0.f, 0.f};
    if (upd) {
#pragma unroll
        for (int r = 0; r < 8; ++r) {
            int k2 = w * 8 + r;
            vf4 wv;
            if (REGW) wv = wreg[r];
            else      wv = *(const vf4*)(W + (size_t)(p * 64 + k2) * Nout + c0);
            wv = DEC * wv - usL[k2] * vpv;
            if (REGW) wreg[r] = wv;
            else      st_cv4(W + (size_t)(p * 64 + k2) * Nout + c0, wv);
            ap += hsL[k2] * wv; aq += hqL[k2] * wv;
        }
    } else {
#pragma unroll
        for (int r = 0; r < 8; ++r) {
            int k2 = w * 8 + r;
            vf4 wv;
            if (REGW) wv = wreg[r];
            else      wv = *(const vf4*)(W + (size_t)(p * 64 + k2) * Nout + c0);
            ap += hsL[k2] * wv; aq += hqL[k2] * wv;
        }
    }
    if (upd && bblk == 0) {   // bias of THIS output layer, read next phase
        int c = tid * 4;
        if (c < Nout) {
            vf4 dq = ld4_cv(vprev + c);
            vf4 bv = ld4_cv(bl + c);
            st_cv4(bl + c, DEC * bv - LRC * dq);
        }
    }
    s4[w * 64 + lane] = ap;
    s4[512 + w * 64 + lane] = aq;
    __syncthreads();
    if (w == 0) {
        vf4 sp = s4[lane], sq4 = s4[512 + lane];
#pragma unroll
        for (int q = 1; q < 8; ++q) { sp += s4[q * 64 + lane]; sq4 += s4[512 + q * 64 + lane]; }
        st_cv(zoutTP + (size_t)(c0 + 0) * 32 + p, sp.x);
        st_cv(zoutTP + (size_t)(c0 + 1) * 32 + p, sp.y);
        st_cv(zoutTP + (size_t)(c0 + 2) * 32 + p, sp.z);
        st_cv(zoutTP + (size_t)(c0 + 3) * 32 + p, sp.w);
        st_cv(zoutTQ + (size_t)(c0 + 0) * 32 + p, sq4.x);
        st_cv(zoutTQ + (size_t)(c0 + 1) * 32 + p, sq4.y);
        st_cv(zoutTQ + (size_t)(c0 + 2) * 32 + p, sq4.z);
        st_cv(zoutTQ + (size_t)(c0 + 3) * 32 + p, sq4.w);
    }
}

// ---- W^T backward with register row-slice (NV vf4 per thread, K = NV*256) ----
template<int NV>
__device__ __forceinline__ void bwdreg(vf4* wrow, int bblk, int tid, int w, int lane,
        float* SM, float* sqw,
        const float* dinP, const float* dinQ,           // current-step deltas (staged)
        const float* vprevq, const float* uprevq,       // prev-step update vectors
        const float* hP, const float* hQ, bool upd,     // gates (current step)
        float* doutP, float* doutQ, float* slot) {
    const int K = NV * 256;
    float* dsP = SM; float* dsQ = SM + K;
    int j = bblk * 8 + w;
    int k4 = tid * 4;
    bool stg = (k4 < K);
    vf4 vP, vQ;
    if (stg) { vP = ld4_nw(dinP + k4); vQ = ld4_nw(dinQ + k4); }
    vf4 vq[NV]; float u;
    if (upd) {
#pragma unroll
        for (int i = 0; i < NV; ++i) vq[i] = ld4_nw(vprevq + lane * 4 + i * 256);
        u = ld_nw(uprevq + j);
    }
    float gP, gQ;
    if (lane == 0) { gP = ld_nw(hP + j); gQ = ld_nw(hQ + j); }
    vmwait();
    if (stg) { PIN(vP); PIN(vQ); }
    if (upd) {
#pragma unroll
        for (int i = 0; i < NV; ++i) PIN(vq[i]);
        PIN(u);
    }
    if (lane == 0) { PIN(gP); PIN(gQ); }
    if (stg) { *(vf4*)(dsP + k4) = vP; *(vf4*)(dsQ + k4) = vQ; }
    if (upd) {
        float ul = LRC * u;
#pragma unroll
        for (int i = 0; i < NV; ++i) wrow[i] = DEC * wrow[i] - ul * vq[i];
    }
    __syncthreads();
    float ap = 0.f, aq = 0.f;
#pragma unroll
    for (int i = 0; i < NV; ++i) {
        int k0 = lane * 4 + i * 256;
        vf4 wv = wrow[i];
        ap += wv.x * dsP[k0] + wv.y * dsP[k0 + 1] + wv.z * dsP[k0 + 2] + wv.w * dsP[k0 + 3];
        aq += wv.x * dsQ[k0] + wv.y * dsQ[k0 + 1] + wv.z * dsQ[k0 + 2] + wv.w * dsQ[k0 + 3];
    }
#pragma unroll
    for (int off = 32; off > 0; off >>= 1) {
        ap += __shfl_down(ap, off);
        aq += __shfl_down(aq, off);
    }
    if (lane == 0) {
        float dp = (gP > 0.f) ? ap : 0.f;
        float dq = (gQ > 0.f) ? DEC * aq : 0.f;
        st_cv(doutP + j, dp); st_cv(doutQ + j, dq); sqw[w] = dp * dp;
    }
    __syncthreads();
    if (tid == 0) {
        float t = 0.f;
#pragma unroll
        for (int q = 0; q < 8; ++q) t += sqw[q];
        st_cv(slot + bblk, t);
    }
    __syncthreads();
}

// ---------------- persistent TTT kernel: weights register-resident ----------------
__global__ __launch_bounds__(512, 2) void k_ttt(const float* __restrict__ x,
        float* __restrict__ W1, float* __restrict__ b1,
        float* __restrict__ W2, float* __restrict__ b2,
        float* __restrict__ W3, float* __restrict__ b3,
        float* __restrict__ W4, float* __restrict__ b4,
        float* __restrict__ wsf, const int* __restrict__ flag, int* __restrict__ bar) {
    if (*flag == 0) return;
    const int b = blockIdx.x, tid = threadIdx.x;
    const int w = tid >> 6, lane = tid & 63;
    __shared__ float SM[5376];
    __shared__ float cnd[16];
    __shared__ float sqw[8];
    int bi = 0;

    const int g = b >> 5, p = b & 31;
    const int c0g = g * 256 + lane * 4;
    const int kb1 = p * 24 + w * 3;
    const int j = b * 8 + w;

    // ---- init: load register weight slices (pristine, cached loads) ----
    vf4 w1f[3], w2f[8], w3f[8], w2b[8], w3b[8], w4b[3];
#pragma unroll
    for (int i = 0; i < 3; ++i) w1f[i] = *(const vf4*)(W1 + (size_t)(kb1 + i) * 2048 + c0g);
#pragma unroll
    for (int r = 0; r < 8; ++r) w2f[r] = *(const vf4*)(W2 + (size_t)(p * 64 + w * 8 + r) * 2048 + c0g);
#pragma unroll
    for (int r = 0; r < 8; ++r) w3f[r] = *(const vf4*)(W3 + (size_t)(p * 64 + w * 8 + r) * 2048 + c0g);
#pragma unroll
    for (int i = 0; i < 8; ++i) w2b[i] = *(const vf4*)(W2 + (size_t)j * 2048 + lane * 4 + i * 256);
#pragma unroll
    for (int i = 0; i < 8; ++i) w3b[i] = *(const vf4*)(W3 + (size_t)j * 2048 + lane * 4 + i * 256);
#pragma unroll
    for (int i = 0; i < 3; ++i) w4b[i] = *(const vf4*)(W4 + (size_t)j * 768 + lane * 4 + i * 256);

    for (int s = 0; s < 1024; ++s) {
        const float* xt = x + (size_t)s * 3072;
        const float* xp = x + (size_t)(s > 0 ? s - 1 : 0) * 3072;
        int cur = s & 1, prv = (s - 1) & 1;
        float* h1q_cur = wsf + (cur ? OFF_H1Q1 : OFF_H1Q0);
        const float* h1q_prev = wsf + (cur ? OFF_H1Q0 : OFF_H1Q1);
        float* h2q_cur = wsf + (cur ? OFF_H2Q1 : OFF_H2Q0);
        const float* h2q_prev = wsf + (cur ? OFF_H2Q0 : OFF_H2Q1);
        float* h3q_cur = wsf + (cur ? OFF_H3Q1 : OFF_H3Q0);
        const float* h3q_prev = wsf + (cur ? OFF_H3Q0 : OFF_H3Q1);
        float* d2q_cur = wsf + (cur ? OFF_D2Q1 : OFF_D2Q0);
        const float* d2q_prev = wsf + (cur ? OFF_D2Q0 : OFF_D2Q1);
        float* d3q_cur = wsf + (cur ? OFF_D3Q1 : OFF_D3Q0);
        const float* d3q_prev = wsf + (cur ? OFF_D3Q0 : OFF_D3Q1);
        float* d4q_cur = wsf + (cur ? OFF_D4Q1 : OFF_D4Q0);
        const float* d4q_prev = wsf + (cur ? OFF_D4Q0 : OFF_D4Q1);
        float cond = 0.f;

        // ===== phase A: cond + W1f update + z1 partials =====
        {
            vf4* s4 = (vf4*)SM;
            float a0 = xt[kb1 + 0], a1 = xt[kb1 + 1], a2 = xt[kb1 + 2];
            vf4 dv = {0.f, 0.f, 0.f, 0.f};
            float u0 = 0.f, u1 = 0.f, u2 = 0.f;
            if (s > 0) {
                dv = ld4_nw(wsf + OFF_D1Q + c0g);
                vf4 sl4; float nv;
                if (w < 3) {
                    const float* sl = wsf + (w == 0 ? OFF_SL1 : (w == 1 ? OFF_SL2 : OFF_SL3));
                    sl4 = ld4_nw(sl + lane * 4);
                }
                if (w == 3 && lane < 8)
                    nv = ld_nw(lane < 7 ? (wsf + OFF_NSQ + lane) : (wsf + OFF_BUF + prv));
                vmwait();
                PIN(dv);
                if (w < 3) PIN(sl4);
                if (w == 3 && lane < 8) PIN(nv);
                u0 = LRC * xp[kb1 + 0]; u1 = LRC * xp[kb1 + 1]; u2 = LRC * xp[kb1 + 2];
                if (w < 3) {
                    float v = sum4(sl4);
#pragma unroll
                    for (int off = 32; off > 0; off >>= 1) v += __shfl_down(v, off);
                    if (lane == 0) cnd[w] = v;
                } else if (w == 3 && lane < 8) {
                    cnd[3 + lane] = nv;
                }
                __syncthreads();
                float nd1 = sqrtf(cnd[0]), nd2 = sqrtf(cnd[1]), nd3 = sqrtf(cnd[2]);
                float nx = sqrtf(cnd[3]), nh1 = sqrtf(cnd[4]), nh2 = sqrtf(cnd[5]), nh3 = sqrtf(cnd[6]);
                float nd4 = sqrtf(cnd[7] + cnd[8] + cnd[9]);
                float bufold = cnd[10];
                float surprise = nx * nd1 + nd1 + nh1 * nd2 + nd2 + nh2 * nd3 + nd3 + nh3 * nd4 + nd4;
                float bufnew = (s == 1) ? surprise : (0.9f * bufold + 0.1f * surprise);
                cond = (bufnew > 0.1f) ? 1.f : 0.f;
                if (b == 0 && tid == 0) st_cv(wsf + OFF_BUF + cur, bufnew);
            }
            if (cond != 0.f) {
                w1f[0] = DEC * w1f[0] - u0 * dv;
                w1f[1] = DEC * w1f[1] - u1 * dv;
                w1f[2] = DEC * w1f[2] - u2 * dv;
                if (b == 0) {
                    int c = tid * 4;
                    vf4 dq = ld4_cv(wsf + OFF_D1Q + c);
                    vf4 bv = ld4_cv(b1 + c);
                    st_cv4(b1 + c, DEC * bv - LRC * dq);
                }
            }
            vf4 acc = a0 * w1f[0] + a1 * w1f[1] + a2 * w1f[2];
            s4[w * 64 + lane] = acc;
            __syncthreads();
            if (w == 0) {
                vf4 t = s4[lane];
#pragma unroll
                for (int q = 1; q < 8; ++q) t += s4[q * 64 + lane];
                st_cv(wsf + OFF_Z1T + (size_t)(c0g + 0) * 32 + p, t.x);
                st_cv(wsf + OFF_Z1T + (size_t)(c0g + 1) * 32 + p, t.y);
                st_cv(wsf + OFF_Z1T + (size_t)(c0g + 2) * 32 + p, t.z);
                st_cv(wsf + OFF_Z1T + (size_t)(c0g + 3) * 32 + p, t.w);
            }
        }
        gbar(bar, bi++);
        bool upd = (cond != 0.f);

        // ===== phase B: layer 2 (register W2f) =====
        fwd2phase<true>(w2f, b, tid, w, lane, SM, wsf + OFF_Z1T, nullptr, b1, nullptr, 2048,
                        wsf + OFF_Z2TP, wsf + OFF_Z2TQ, h1q_prev, d2q_prev, b2, upd);
        gbar(bar, bi++);

        // ===== phase C: layer 3 (register W3f) =====
        fwd2phase<true>(w3f, b, tid, w, lane, SM, wsf + OFF_Z2TP, wsf + OFF_Z2TQ, b2, nullptr, 2048,
                        wsf + OFF_Z3TP, wsf + OFF_Z3TQ, h2q_prev, d3q_prev, b3, upd);
        gbar(bar, bi++);

        // ===== phase D: layer 4 (96 blocks, memory W4) + h finalize/norms (spares) =====
        if (b < 96) {
            fwd2phase<false>(nullptr, b, tid, w, lane, SM, wsf + OFF_Z3TP, wsf + OFF_Z3TQ, b3, W4, 768,
                             wsf + OFF_Z4TP, wsf + OFF_Z4TQ, h3q_prev, d4q_prev, b4, upd);
        } else {
            int idx = b - 96;
            float* partP = SM;            // [128][4]
            float* partQ = SM + 512;
            float* biasD = SM + 1024;     // [128]
            if (idx < 16) {
                int base = idx * 128, el = tid >> 2, c2 = tid & 3;
                const float* zl = wsf + OFF_Z1T + (size_t)(base + el) * 32 + c2 * 8;
                vf4 za = ld4_nw(zl), zb = ld4_nw(zl + 4);
                vf4 bb; if (tid < 32) bb = ld4_nw(b1 + base + tid * 4);
                vmwait(); PIN(za); PIN(zb); if (tid < 32) PIN(bb);
                partP[el * 4 + c2] = sum4(za) + sum4(zb);
                if (tid < 32) *(vf4*)(biasD + tid * 4) = bb;
                __syncthreads();
                if (tid < 128) {
                    float sv = partP[tid * 4] + partP[tid * 4 + 1] + partP[tid * 4 + 2] + partP[tid * 4 + 3];
                    float h = fmaxf(sv + biasD[tid], 0.f);
                    st_cv(wsf + OFF_H1F + base + tid, h);
                    st_cv(h1q_cur + base + tid, DEC * h);
                }
            } else if (idx < 48) {
                int l3 = (idx >= 32);
                int base = (idx - (l3 ? 32 : 16)) * 128, el = tid >> 2, c2 = tid & 3;
                const float* ZP = wsf + (l3 ? OFF_Z3TP : OFF_Z2TP);
                const float* ZQ = wsf + (l3 ? OFF_Z3TQ : OFF_Z2TQ);
                const float* bb_ = l3 ? b3 : b2;
                const float* zp0 = ZP + (size_t)(base + el) * 32 + c2 * 8;
                const float* zq0 = ZQ + (size_t)(base + el) * 32 + c2 * 8;
                vf4 pa = ld4_nw(zp0), pb = ld4_nw(zp0 + 4);
                vf4 qa = ld4_nw(zq0), qb = ld4_nw(zq0 + 4);
                vf4 bb; if (tid < 32) bb = ld4_nw(bb_ + base + tid * 4);
                vmwait(); PIN(pa); PIN(pb); PIN(qa); PIN(qb); if (tid < 32) PIN(bb);
                partP[el * 4 + c2] = sum4(pa) + sum4(pb);
                partQ[el * 4 + c2] = sum4(qa) + sum4(qb);
                if (tid < 32) *(vf4*)(biasD + tid * 4) = bb;
                __syncthreads();
                if (tid < 128) {
                    float sp = partP[tid * 4] + partP[tid * 4 + 1] + partP[tid * 4 + 2] + partP[tid * 4 + 3];
                    float sq = partQ[tid * 4] + partQ[tid * 4 + 1] + partQ[tid * 4 + 2] + partQ[tid * 4 + 3];
                    float bv = biasD[tid];
                    if (l3) {
                        st_cv(wsf + OFF_H3F + base + tid, fmaxf(sp + bv, 0.f));
                        st_cv(h3q_cur + base + tid, fmaxf(DEC * (sq + bv), 0.f));
                    } else {
                        st_cv(wsf + OFF_H2F + base + tid, fmaxf(sp + bv, 0.f));
                        st_cv(h2q_cur + base + tid, fmaxf(DEC * (sq + bv), 0.f));
                    }
                }
            } else if (idx == 48) {          // ||x||^2
                float v = 0.f;
                for (int e = tid; e < 768; e += 512) { float xv = xt[e]; v += xv * xv; }
                float t = block_reduce_512(v);
                if (tid == 0) st_cv(wsf + OFF_NSQ + 0, t);
            } else if (idx < 52) {           // ||h1||^2 / ||h2||^2 / ||h3||^2
                const float* ZT = (idx == 49) ? (wsf + OFF_Z1T) : (idx == 50 ? (wsf + OFF_Z2TP) : (wsf + OFF_Z3TP));
                const float* bb_ = (idx == 49) ? b1 : (idx == 50 ? b2 : b3);
                int nk = idx - 48;
                float acc = 0.f;
#pragma unroll
                for (int pass = 0; pass < 4; ++pass) {
                    int e = pass * 512 + tid;
                    const float* zl = ZT + (size_t)e * 32;
                    vf4 z0 = ld4_nw(zl), z1 = ld4_nw(zl + 4), z2 = ld4_nw(zl + 8), z3 = ld4_nw(zl + 12);
                    vf4 z4 = ld4_nw(zl + 16), z5 = ld4_nw(zl + 20), z6 = ld4_nw(zl + 24), z7 = ld4_nw(zl + 28);
                    float bv = ld_nw(bb_ + e);
                    vmwait();
                    PIN(z0); PIN(z1); PIN(z2); PIN(z3); PIN(z4); PIN(z5); PIN(z6); PIN(z7); PIN(bv);
                    float sv = sum4(z0) + sum4(z1) + sum4(z2) + sum4(z3)
                             + sum4(z4) + sum4(z5) + sum4(z6) + sum4(z7);
                    float h = fmaxf(sv + bv, 0.f);
                    acc += h * h;
                }
                float t = block_reduce_512(acc);
                if (tid == 0) st_cv(wsf + OFF_NSQ + nk, t);
            }
        }
        gbar(bar, bi++);

        // ===== phase DD: finalize d4 (blocks 0..2), |d4|^2 partials =====
        if (b < 3) {
            int t2 = tid >> 1, dir = tid & 1;
            int e = b * 256 + t2;
            const float* Z = wsf + (dir ? OFF_Z4TQ : OFF_Z4TP) + (size_t)e * 32;
            vf4 z0 = ld4_nw(Z), z1 = ld4_nw(Z + 4), z2 = ld4_nw(Z + 8), z3 = ld4_nw(Z + 12);
            vf4 z4 = ld4_nw(Z + 16), z5 = ld4_nw(Z + 20), z6 = ld4_nw(Z + 24), z7 = ld4_nw(Z + 28);
            float bv = ld_nw(b4 + e);
            vmwait();
            PIN(z0); PIN(z1); PIN(z2); PIN(z3); PIN(z4); PIN(z5); PIN(z6); PIN(z7); PIN(bv);
            float ssum = sum4(z0) + sum4(z1) + sum4(z2) + sum4(z3)
                       + sum4(z4) + sum4(z5) + sum4(z6) + sum4(z7);
            float tv = xt[e];
            float d;
            if (dir == 0) d = 2.f * ((ssum + bv) - tv) * (1.f / 768.f);
            else          d = 2.f * (DEC * (ssum + bv) - tv) * (1.f / 768.f);
            if (dir == 0) st_cv(wsf + OFF_D4F + e, d);
            else          st_cv(d4q_cur + e, d);
            float sq2 = (dir == 0) ? d * d : 0.f;
            float t = block_reduce_512(sq2);
            if (tid == 0) st_cv(wsf + OFF_NSQ + 4 + b, t);
        }
        gbar(bar, bi++);

        // ===== phase E: bwd L4 (register W4b) =====
        bwdreg<3>(w4b, b, tid, w, lane, SM, sqw,
                  wsf + OFF_D4F, d4q_cur, d4q_prev, h3q_prev,
                  wsf + OFF_H3F, h3q_cur, upd,
                  wsf + OFF_D3F, d3q_cur, wsf + OFF_SL3);
        gbar(bar, bi++);

        // ===== phase F: bwd L3 (register W3b) =====
        bwdreg<8>(w3b, b, tid, w, lane, SM, sqw,
                  wsf + OFF_D3F, d3q_cur, d3q_prev, h2q_prev,
                  wsf + OFF_H2F, h2q_cur, upd,
                  wsf + OFF_D2F, d2q_cur, wsf + OFF_SL2);
        gbar(bar, bi++);

        // ===== phase G: bwd L2 (register W2b) =====
        bwdreg<8>(w2b, b, tid, w, lane, SM, sqw,
                  wsf + OFF_D2F, d2q_cur, d2q_prev, h1q_prev,
                  wsf + OFF_H1F, h1q_cur, upd,
                  wsf + OFF_D1F, wsf + OFF_D1Q, wsf + OFF_SL1);
        gbar(bar, bi++);
    }

    // ===== epilogue: cond(1023) + final update + writeback =====
    {
        // cond for step 1023 (slots: parity 1)
        vf4 sl4; float nv;
        if (w < 3) {
            const float* sl = wsf + (w == 0 ? OFF_SL1 : (w == 1 ? OFF_SL2 : OFF_SL3));
            sl4 = ld4_nw(sl + lane * 4);
        }
        if (w == 3 && lane < 8)
            nv = ld_nw(lane < 7 ? (wsf + OFF_NSQ + lane) : (wsf + OFF_BUF + 1));
        vmwait();
        if (w < 3) PIN(sl4);
        if (w == 3 && lane < 8) PIN(nv);
        if (w < 3) {
            float v = sum4(sl4);
#pragma unroll
            for (int off = 32; off > 0; off >>= 1) v += __shfl_down(v, off);
            if (lane == 0) cnd[w] = v;
        } else if (w == 3 && lane < 8) {
            cnd[3 + lane] = nv;
        }
        __syncthreads();
        float nd1 = sqrtf(cnd[0]), nd2 = sqrtf(cnd[1]), nd3 = sqrtf(cnd[2]);
        float nx = sqrtf(cnd[3]), nh1 = sqrtf(cnd[4]), nh2 = sqrtf(cnd[5]), nh3 = sqrtf(cnd[6]);
        float nd4 = sqrtf(cnd[7] + cnd[8] + cnd[9]);
        float bufold = cnd[10];
        float surprise = nx * nd1 + nd1 + nh1 * nd2 + nd2 + nh2 * nd3 + nd3 + nh3 * nd4 + nd4;
        float bufnew = 0.9f * bufold + 0.1f * surprise;
        if (bufnew > 0.1f) {
            const float* xt1023 = x + (size_t)1023 * 3072;
            const float* h1q1 = wsf + OFF_H1Q1;
            const float* h2q1 = wsf + OFF_H2Q1;
            const float* h3q1 = wsf + OFF_H3Q1;
            const float* d2q1 = wsf + OFF_D2Q1;
            const float* d3q1 = wsf + OFF_D3Q1;
            const float* d4q1 = wsf + OFF_D4Q1;
            // W1f
            {
                vf4 dv = ld4_cv(wsf + OFF_D1Q + c0g);
                float u0 = LRC * xt1023[kb1 + 0], u1 = LRC * xt1023[kb1 + 1], u2 = LRC * xt1023[kb1 + 2];
                w1f[0] = DEC * w1f[0] - u0 * dv;
                w1f[1] = DEC * w1f[1] - u1 * dv;
                w1f[2] = DEC * w1f[2] - u2 * dv;
            }
            // W2f
            {
                vf4 ha = ld4_cv(h1q1 + p * 64 + w * 8);
                vf4 hb = ld4_cv(h1q1 + p * 64 + w * 8 + 4);
                vf4 vpv = ld4_cv(d2q1 + c0g);
                float us_[8] = {ha.x, ha.y, ha.z, ha.w, hb.x, hb.y, hb.z, hb.w};
#pragma unroll
                for (int r = 0; r < 8; ++r) w2f[r] = DEC * w2f[r] - (LRC * us_[r]) * vpv;
            }
            // W3f
            {
                vf4 ha = ld4_cv(h2q1 + p * 64 + w * 8);
                vf4 hb = ld4_cv(h2q1 + p * 64 + w * 8 + 4);
                vf4 vpv = ld4_cv(d3q1 + c0g);
                float us_[8] = {ha.x, ha.y, ha.z, ha.w, hb.x, hb.y, hb.z, hb.w};
#pragma unroll
                for (int r = 0; r < 8; ++r) w3f[r] = DEC * w3f[r] - (LRC * us_[r]) * vpv;
            }
            // W4 (memory): rows b*8..+8, cols tid*4 (tid<192)
            if (tid < 192) {
                vf4 dv4 = ld4_cv(d4q1 + tid * 4);
                vf4 ha = ld4_cv(h3q1 + b * 8);
                vf4 hb = ld4_cv(h3q1 + b * 8 + 4);
                float us_[8] = {ha.x, ha.y, ha.z, ha.w, hb.x, hb.y, hb.z, hb.w};
#pragma unroll
                for (int r = 0; r < 8; ++r) {
                    float* wp = W4 + (size_t)(b * 8 + r) * 768 + tid * 4;
                    vf4 wv = ld4_cv(wp);
                    st_cv4(wp, DEC * wv - (LRC * us_[r]) * dv4);
                }
            }
            // biases
            int c = tid * 4;
            if (b == 0) {
                vf4 dq = ld4_cv(wsf + OFF_D1Q + c);
                vf4 bv = ld4_cv(b1 + c);
                st_cv4(b1 + c, DEC * bv - LRC * dq);
            } else if (b == 1) {
                vf4 dq = ld4_cv(d2q1 + c);
                vf4 bv = ld4_cv(b2 + c);
                st_cv4(b2 + c, DEC * bv - LRC * dq);
            } else if (b == 2) {
                vf4 dq = ld4_cv(d3q1 + c);
                vf4 bv = ld4_cv(b3 + c);
                st_cv4(b3 + c, DEC * bv - LRC * dq);
            } else if (b == 3 && tid < 192) {
                vf4 dq = ld4_cv(d4q1 + c);
                vf4 bv = ld4_cv(b4 + c);
                st_cv4(b4 + c, DEC * bv - LRC * dq);
            }
        }
        // writeback fwd register copies (plain stores; kernel-end flush publishes)
#pragma unroll
        for (int i = 0; i < 3; ++i) *(vf4*)(W1 + (size_t)(kb1 + i) * 2048 + c0g) = w1f[i];
#pragma unroll
        for (int r = 0; r < 8; ++r) *(vf4*)(W2 + (size_t)(p * 64 + w * 8 + r) * 2048 + c0g) = w2f[r];
#pragma unroll
        for (int r = 0; r < 8; ++r) *(vf4*)(W3 + (size_t)(p * 64 + w * 8 + r) * 2048 + c0g) = w3f[r];
    }
}

// ---------- final batch forward: fp32 tiled GEMM C = act(A@W + bias) ----------
__global__ __launch_bounds__(256) void k_gemm(const float* __restrict__ A,
                                              const float* __restrict__ W,
                                              const float* __restrict__ bias,
                                              float* __restrict__ C,
                                              int M, int N, int K, int do_relu) {
    __shared__ float sA[16][64];
    __shared__ float sB[16][128];
    int bn = blockIdx.x, bm = blockIdx.y;
    int m0 = bm * 64, n0 = bn * 128;
    int tid = threadIdx.x;
    int tx = tid & 31, ty = tid >> 5;
    float acc[8][4];
#pragma unroll
    for (int i = 0; i < 8; ++i)
#pragma unroll
        for (int jj = 0; jj < 4; ++jj) acc[i][jj] = 0.f;

    for (int kt = 0; kt < K; kt += 16) {
        {
            int r = tid >> 2, cc = (tid & 3) * 4;
            const float4 a4 = *(const float4*)(A + (size_t)(m0 + r) * K + kt + cc);
            sA[cc + 0][r] = a4.x; sA[cc + 1][r] = a4.y; sA[cc + 2][r] = a4.z; sA[cc + 3][r] = a4.w;
        }
        {
            int r = tid >> 5, cc = (tid & 31) * 4;
            *(float4*)(&sB[r][cc]) = *(const float4*)(W + (size_t)(kt + r) * N + n0 + cc);
            *(float4*)(&sB[r + 8][cc]) = *(const float4*)(W + (size_t)(kt + r + 8) * N + n0 + cc);
        }
        __syncthreads();
#pragma unroll
        for (int k = 0; k < 16; ++k) {
            float av[8];
#pragma unroll
            for (int i = 0; i < 8; ++i) av[i] = sA[k][ty * 8 + i];
            float bx = sB[k][tx * 4 + 0], by = sB[k][tx * 4 + 1];
            float bz = sB[k][tx * 4 + 2], bw = sB[k][tx * 4 + 3];
#pragma unroll
            for (int i = 0; i < 8; ++i) {
                acc[i][0] += av[i] * bx; acc[i][1] += av[i] * by;
                acc[i][2] += av[i] * bz; acc[i][3] += av[i] * bw;
            }
        }
        __syncthreads();
    }
    float bx = bias[n0 + tx * 4 + 0], by = bias[n0 + tx * 4 + 1];
    float bz = bias[n0 + tx * 4 + 2], bw = bias[n0 + tx * 4 + 3];
#pragma unroll
    for (int i = 0; i < 8; ++i) {
        int m = m0 + ty * 8 + i;
        float4 v;
        v.x = acc[i][0] + bx; v.y = acc[i][1] + by;
        v.z = acc[i][2] + bz; v.w = acc[i][3] + bw;
        if (do_relu) {
            v.x = fmaxf(v.x, 0.f); v.y = fmaxf(v.y, 0.f);
            v.z = fmaxf(v.z, 0.f); v.w = fmaxf(v.w, 0.f);
        }
        *(float4*)(C + (size_t)m * N + n0 + tx * 4) = v;
    }
}

__global__ __launch_bounds__(128) void k_colsum(const float* __restrict__ Y,
                                                float* __restrict__ out) {
    int c = blockIdx.x * 128 + threadIdx.x;
    int r0 = blockIdx.y * 128;
    float s = 0.f;
    for (int r = 0; r < 128; ++r) s += Y[(size_t)(r0 + r) * 768 + c];
    out[blockIdx.y * 768 + c] = s;
}

__global__ __launch_bounds__(768) void k_out(const float* __restrict__ msum,
                                             float* __restrict__ out) {
    int c = threadIdx.x;
    float s = 0.f;
#pragma unroll
    for (int i = 0; i < 32; ++i) s += msum[i * 768 + c];
    out[c] = s * (1.f / 4096.f);
}

extern "C" void kernel_launch(void* const* d_in, const int* in_sizes, int n_in,
                              void* d_out, int out_size, void* d_ws, size_t ws_size,
                              hipStream_t stream) {
    const float* x = (const float*)d_in[0];
    float* W1 = (float*)d_in[1];
    float* b1 = (float*)d_in[2];
    float* W2 = (float*)d_in[3];
    float* b2 = (float*)d_in[4];
    float* W3 = (float*)d_in[5];
    float* b3 = (float*)d_in[6];
    float* W4 = (float*)d_in[7];
    float* b4 = (float*)d_in[8];
    const int* flag = (const int*)d_in[9];
    float* wsf = (float*)d_ws;
    int* bar = (int*)(wsf + OFF_BAR);

    hipMemsetAsync((void*)bar, 0, 1024 * sizeof(int), stream);

    void* args[] = {(void*)&x, (void*)&W1, (void*)&b1, (void*)&W2, (void*)&b2,
                    (void*)&W3, (void*)&b3, (void*)&W4, (void*)&b4,
                    (void*)&wsf, (void*)&flag, (void*)&bar};
    hipLaunchCooperativeKernel((void*)k_ttt, dim3(256), dim3(512), args, 0, stream);

    float* HA = wsf + OFF_HA;
    float* HB = wsf + OFF_HB;
    for (int ch = 0; ch < 4; ++ch) {
        const float* Xc = x + (size_t)ch * 1024 * 768;
        k_gemm<<<dim3(16, 16), 256, 0, stream>>>(Xc, W1, b1, HA, 1024, 2048, 768, 1);
        k_gemm<<<dim3(16, 16), 256, 0, stream>>>(HA, W2, b2, HB, 1024, 2048, 2048, 1);
        k_gemm<<<dim3(16, 16), 256, 0, stream>>>(HB, W3, b3, HA, 1024, 2048, 2048, 1);
        k_gemm<<<dim3(6, 16), 256, 0, stream>>>(HA, W4, b4, HB, 1024, 768, 2048, 0);
        k_colsum<<<dim3(6, 8), 128, 0, stream>>>(HB, wsf + OFF_MSUM + (size_t)ch * 8 * 768);
    }
    k_out<<<1, 768, 0, stream>>>(wsf + OFF_MSUM, (float*)d_out);
}